// Round 1
// baseline (103.157 us; speedup 1.0000x reference)
//
#include <hip/hip_runtime.h>
#include <stdint.h>

// HypervectorEngine: signal (512,8192) f32 -> sparse (512,4096) f32 in {-1,0,+1}
//
// Pipeline (bit-exact replica of the JAX reference):
//  1. idx[s] = trunc(s * (8191/99)) for s in 0..99        (jnp.linspace + astype)
//  2. seed[b][s] = s ^ rne(signal[b][idx[s]] * 1000)       (round-half-even)
//  3. hv(seed) = threefry-derived +/-1 vector of length 4096
//     - fold_in(key(42), seed): cipher k=(0,42), x=(0,seed) -> folded key
//     - bernoulli(.5): element i bit = top bit of random 32 bits
//       MODE: jax_threefry_partitionable=True (modern default):
//             bits(i) = o0 ^ o1 of cipher(folded_key, (0, i))
//       (if absmax ~2: swap rbits32 to the legacy split-iota path:
//        i<2048 -> o0 of cipher(i, i+2048); else o1 of cipher(i-2048, i))
//  4. combined[b][d] = sum over s of hv
//  5. top-k 2048 by |combined|, stable ties (lower index wins), emit sign.
//
// Seed-collapse optimization: seed = pos^val < 1024 always, so only 1024
// distinct hypervectors exist. Build int8 table[1024][4096] (4 MB, fits
// per-XCD L2) once per launch in d_ws, then gather-sum.

#define B_ROWS 512
#define SIG_L  8192
#define DIM    4096
#define NS     100
#define NKEY   2048
#define NSEED  1024

__device__ __forceinline__ void tf2x32(uint32_t k0, uint32_t k1,
                                       uint32_t& x0, uint32_t& x1) {
  const uint32_t k2 = k0 ^ k1 ^ 0x1BD11BDAu;
  x0 += k0; x1 += k1;
#define TF_RND(r) { x0 += x1; x1 = (x1 << (r)) | (x1 >> (32 - (r))); x1 ^= x0; }
  TF_RND(13) TF_RND(15) TF_RND(26) TF_RND(6)
  x0 += k1; x1 += k2 + 1u;
  TF_RND(17) TF_RND(29) TF_RND(16) TF_RND(24)
  x0 += k2; x1 += k0 + 2u;
  TF_RND(13) TF_RND(15) TF_RND(26) TF_RND(6)
  x0 += k0; x1 += k1 + 3u;
  TF_RND(17) TF_RND(29) TF_RND(16) TF_RND(24)
  x0 += k1; x1 += k2 + 4u;
  TF_RND(13) TF_RND(15) TF_RND(26) TF_RND(6)
  x0 += k2; x1 += k0 + 5u;
#undef TF_RND
}

// 32 random bits for element i under folded key (partitionable path).
__device__ __forceinline__ uint32_t rbits32(uint32_t k0, uint32_t k1, uint32_t i) {
  uint32_t x0 = 0u, x1 = i;
  tf2x32(k0, k1, x0, x1);
  return x0 ^ x1;
}

// ---- Kernel A: build int8 +/-1 table[seed][dim], one block per seed ----
__global__ __launch_bounds__(256) void build_table_kernel(int8_t* __restrict__ table) {
  const int seed = blockIdx.x;
  __shared__ uint32_t kk[2];
  if (threadIdx.x == 0) {
    uint32_t x0 = 0u, x1 = (uint32_t)seed;   // fold_in: cipher((0,42),(0,seed))
    tf2x32(0u, 42u, x0, x1);
    kk[0] = x0; kk[1] = x1;
  }
  __syncthreads();
  const uint32_t k0 = kk[0], k1 = kk[1];
  const int base = threadIdx.x * 16;         // 16 consecutive dims per thread
  uint32_t w[4];
#pragma unroll
  for (int j = 0; j < 4; ++j) {
    uint32_t acc = 0u;
#pragma unroll
    for (int q = 0; q < 4; ++q) {
      uint32_t bits = rbits32(k0, k1, (uint32_t)(base + j * 4 + q));
      // bernoulli true (uniform<0.5) iff top bit == 0 -> +1 ; else -1
      uint32_t byte = (bits >> 31) ? 0xFFu : 0x01u;
      acc |= byte << (8 * q);
    }
    w[j] = acc;
  }
  uint4 v; v.x = w[0]; v.y = w[1]; v.z = w[2]; v.w = w[3];
  *(uint4*)(table + (size_t)seed * DIM + base) = v;   // coalesced 16B/lane
}

// ---- Kernel B: per-row combine + stable top-k + write, one block per row ----
template <bool USE_TABLE>
__global__ __launch_bounds__(256) void row_kernel(const float* __restrict__ signal,
                                                  const int8_t* __restrict__ table,
                                                  float* __restrict__ out) {
  const int b = blockIdx.x;
  const int t = threadIdx.x;
  __shared__ int      sseed[NS];
  __shared__ uint32_t sk0[NS], sk1[NS];
  __shared__ int      hist[101];     // |combined| in [0,100]
  __shared__ int      cnts[256];
  __shared__ int      TQ[2];

  if (t < 101) hist[t] = 0;
  if (t < NS) {
    const float step = 8191.0f / 99.0f;            // linspace(0, L-1, 100) step
    float idxf = (float)t * step;
    int   idx  = (int)idxf;                         // astype(int32): trunc
    float v    = signal[b * SIG_L + idx];
    int   val  = __float2int_rn(v * 1000.0f);       // jnp.round: half-to-even
    int   sd   = t ^ val;                           // pos ^ val_seed (< 1024)
    sseed[t] = sd;
    if (!USE_TABLE) {
      uint32_t x0 = 0u, x1 = (uint32_t)sd;
      tf2x32(0u, 42u, x0, x1);
      sk0[t] = x0; sk1[t] = x1;
    }
  }
  __syncthreads();

  int acc[16];
#pragma unroll
  for (int k = 0; k < 16; ++k) acc[k] = 0;
  const int dbase = t * 16;                         // 16 consecutive dims

  for (int s = 0; s < NS; ++s) {
    if (USE_TABLE) {
      const uint4 wv = *(const uint4*)(table + (size_t)sseed[s] * DIM + dbase);
      uint32_t ws[4] = {wv.x, wv.y, wv.z, wv.w};
#pragma unroll
      for (int j = 0; j < 4; ++j) {
        uint32_t u = ws[j];
        acc[4 * j + 0] += (int)(int8_t)(u);
        acc[4 * j + 1] += (int)(int8_t)(u >> 8);
        acc[4 * j + 2] += (int)(int8_t)(u >> 16);
        acc[4 * j + 3] += (int)(int8_t)(u >> 24);
      }
    } else {
      const uint32_t k0 = sk0[s], k1 = sk1[s];
#pragma unroll
      for (int k = 0; k < 16; ++k) {
        uint32_t bits = rbits32(k0, k1, (uint32_t)(dbase + k));
        acc[k] += (bits >> 31) ? -1 : 1;
      }
    }
  }

  // histogram of |combined|
#pragma unroll
  for (int k = 0; k < 16; ++k) {
    int a = acc[k] < 0 ? -acc[k] : acc[k];
    atomicAdd(&hist[a], 1);
  }
  __syncthreads();

  // threshold T and tie quota Q (top-k = all |v|>T plus first Q ties by index)
  if (t == 0) {
    int cum = 0;
    for (int a = 100; a >= 0; --a) {
      int h = hist[a];
      if (cum + h >= NKEY) { TQ[0] = a; TQ[1] = NKEY - cum; break; }
      cum += h;
    }
  }
  __syncthreads();
  const int T = TQ[0];
  const int Q = TQ[1];

  // per-thread tie counts -> exclusive prefix (threads own contiguous dims)
  int c = 0;
#pragma unroll
  for (int k = 0; k < 16; ++k) {
    int a = acc[k] < 0 ? -acc[k] : acc[k];
    c += (a == T);
  }
  cnts[t] = c;
  __syncthreads();
  int prefix = 0;
  for (int u = 0; u < t; ++u) prefix += cnts[u];

  float o[16];
#pragma unroll
  for (int k = 0; k < 16; ++k) {
    int   v = acc[k];
    int   a = v < 0 ? -v : v;
    float sg = v > 0 ? 1.0f : (v < 0 ? -1.0f : 0.0f);
    float r = 0.0f;
    if (a > T) {
      r = sg;
    } else if (a == T) {
      if (prefix < Q) r = sg;     // stable ties: lower index first
      prefix++;
    }
    o[k] = r;
  }
  float4* op = (float4*)(out + (size_t)b * DIM + dbase);
  op[0] = make_float4(o[0],  o[1],  o[2],  o[3]);
  op[1] = make_float4(o[4],  o[5],  o[6],  o[7]);
  op[2] = make_float4(o[8],  o[9],  o[10], o[11]);
  op[3] = make_float4(o[12], o[13], o[14], o[15]);
}

extern "C" void kernel_launch(void* const* d_in, const int* in_sizes, int n_in,
                              void* d_out, int out_size, void* d_ws, size_t ws_size,
                              hipStream_t stream) {
  (void)in_sizes; (void)n_in; (void)out_size;
  const float* signal = (const float*)d_in[0];
  float* out = (float*)d_out;
  const size_t table_bytes = (size_t)NSEED * DIM;   // 4 MB

  if (ws_size >= table_bytes) {
    int8_t* table = (int8_t*)d_ws;
    build_table_kernel<<<NSEED, 256, 0, stream>>>(table);
    row_kernel<true><<<B_ROWS, 256, 0, stream>>>(signal, table, out);
  } else {
    // ws too small: compute ciphers on the fly (slow but correct)
    row_kernel<false><<<B_ROWS, 256, 0, stream>>>(signal, nullptr, out);
  }
}

// Round 2
// 83.931 us; speedup vs baseline: 1.2291x; 1.2291x over previous
//
#include <hip/hip_runtime.h>
#include <stdint.h>

// HypervectorEngine: signal (512,8192) f32 -> sparse (512,4096) f32 in {-1,0,+1}
// Bit-exact replica of JAX reference (threefry partitionable path, verified
// absmax=0 in R1). Seed = pos ^ rne(v*1000) < 1024 -> only 1024 distinct
// hypervectors; build a BIT-PACKED table (1024 x 512 B = 512 KB, L2-resident),
// then per-row gather-sum + exact stable top-k(2048) by |sum| with sign emit.

#define B_ROWS 512
#define SIG_L  8192
#define DIM    4096
#define NS     100
#define NKEY   2048
#define NSEED  1024

__device__ __forceinline__ void tf2x32(uint32_t k0, uint32_t k1,
                                       uint32_t& x0, uint32_t& x1) {
  const uint32_t k2 = k0 ^ k1 ^ 0x1BD11BDAu;
  x0 += k0; x1 += k1;
#define TF_RND(r) { x0 += x1; x1 = (x1 << (r)) | (x1 >> (32 - (r))); x1 ^= x0; }
  TF_RND(13) TF_RND(15) TF_RND(26) TF_RND(6)
  x0 += k1; x1 += k2 + 1u;
  TF_RND(17) TF_RND(29) TF_RND(16) TF_RND(24)
  x0 += k2; x1 += k0 + 2u;
  TF_RND(13) TF_RND(15) TF_RND(26) TF_RND(6)
  x0 += k0; x1 += k1 + 3u;
  TF_RND(17) TF_RND(29) TF_RND(16) TF_RND(24)
  x0 += k1; x1 += k2 + 4u;
  TF_RND(13) TF_RND(15) TF_RND(26) TF_RND(6)
  x0 += k2; x1 += k0 + 5u;
#undef TF_RND
}

// 32 random bits for element i under folded key (partitionable path).
__device__ __forceinline__ uint32_t rbits32(uint32_t k0, uint32_t k1, uint32_t i) {
  uint32_t x0 = 0u, x1 = i;
  tf2x32(k0, k1, x0, x1);
  return x0 ^ x1;
}

// ---- Kernel A: bit-packed table. bit=1 <=> element is -1 (top bit of rbits).
// table[seed] is 512 bytes; byte j holds dims [8j, 8j+8), bit q -> dim 8j+q.
__global__ __launch_bounds__(256) void build_table_kernel(uint16_t* __restrict__ tbl16) {
  const int seed = blockIdx.x;
  __shared__ uint32_t kk[2];
  if (threadIdx.x == 0) {
    uint32_t x0 = 0u, x1 = (uint32_t)seed;   // fold_in: cipher((0,42),(0,seed))
    tf2x32(0u, 42u, x0, x1);
    kk[0] = x0; kk[1] = x1;
  }
  __syncthreads();
  const uint32_t k0 = kk[0], k1 = kk[1];
  const int base = threadIdx.x * 16;         // 16 consecutive dims per thread
  uint32_t bits16 = 0;
#pragma unroll
  for (int k = 0; k < 16; ++k) {
    uint32_t b = rbits32(k0, k1, (uint32_t)(base + k)) >> 31;
    bits16 |= b << k;
  }
  tbl16[seed * 256 + threadIdx.x] = (uint16_t)bits16;   // 128 B/wave coalesced
}

// ---- Kernel B: one block (512 thr) per row; 8 dims/thread ----
template <bool USE_TABLE>
__global__ __launch_bounds__(512) void row_kernel(const float* __restrict__ signal,
                                                  const uint8_t* __restrict__ tbits,
                                                  float* __restrict__ out) {
  const int b = blockIdx.x;
  const int t = threadIdx.x;
  __shared__ int      sseed[NS];
  __shared__ uint32_t sk0[NS], sk1[NS];
  __shared__ int      hist[101];     // |combined| in [0,100]
  __shared__ int      wsum[8];
  __shared__ int      TQ[2];

  if (t < 101) hist[t] = 0;
  if (t < NS) {
    const float step = 8191.0f / 99.0f;            // linspace(0, L-1, 100) step
    float idxf = (float)t * step;
    int   idx  = (int)idxf;                         // astype(int32): trunc
    float v    = signal[b * SIG_L + idx];
    int   val  = __float2int_rn(v * 1000.0f);       // jnp.round: half-to-even
    int   sd   = t ^ val;                           // pos ^ val_seed (< 1024)
    sseed[t] = sd;
    if (!USE_TABLE) {
      uint32_t x0 = 0u, x1 = (uint32_t)sd;
      tf2x32(0u, 42u, x0, x1);
      sk0[t] = x0; sk1[t] = x1;
    }
  }
  __syncthreads();

  // Gather-accumulate: byte-packed counters of "minus" bits per dim.
  // c_lo bytes = dims 8t+0..3, c_hi bytes = dims 8t+4..7.
  uint32_t c_lo = 0, c_hi = 0;
#pragma unroll 4
  for (int s = 0; s < NS; ++s) {
    uint32_t m;
    if (USE_TABLE) {
      m = tbits[(sseed[s] << 9) + t];               // 64 B/wave, L2-hot
    } else {
      m = 0;
      const uint32_t k0 = sk0[s], k1 = sk1[s];
      for (int j = 0; j < 8; ++j)
        m |= (rbits32(k0, k1, (uint32_t)(8 * t + j)) >> 31) << j;
    }
    c_lo += ((m & 0xFu) * 0x00204081u) & 0x01010101u;   // spread 4 bits->4 bytes
    c_hi += ((m >> 4)   * 0x00204081u) & 0x01010101u;
  }

  int acc[8];
#pragma unroll
  for (int k = 0; k < 4; ++k) {
    acc[k]     = NS - 2 * (int)((c_lo >> (8 * k)) & 0xFFu);  // +1 count - (-1) count
    acc[k + 4] = NS - 2 * (int)((c_hi >> (8 * k)) & 0xFFu);
  }

  // Histogram of |combined| (values even, in [0,100]).
#pragma unroll
  for (int k = 0; k < 8; ++k) {
    int a = acc[k] < 0 ? -acc[k] : acc[k];
    atomicAdd(&hist[a], 1);
  }
  __syncthreads();

  // Threshold T + tie quota Q: parallel per-bin suffix sums (101 threads).
  if (t < 101) {
    int cum = 0;
    for (int x = t + 1; x <= 100; ++x) cum += hist[x];   // independent, pipelined
    if (cum < NKEY && cum + hist[t] >= NKEY) { TQ[0] = t; TQ[1] = NKEY - cum; }
  }
  __syncthreads();
  const int T = TQ[0];
  const int Q = TQ[1];

  // Exclusive prefix of tie counts in dim order: wave shfl-scan + wave offsets.
  int cnt = 0;
#pragma unroll
  for (int k = 0; k < 8; ++k) {
    int a = acc[k] < 0 ? -acc[k] : acc[k];
    cnt += (a == T);
  }
  const int lane = t & 63, wv = t >> 6;
  int sc = cnt;
#pragma unroll
  for (int off = 1; off < 64; off <<= 1) {
    int n = __shfl_up(sc, off, 64);
    if (lane >= off) sc += n;
  }
  if (lane == 63) wsum[wv] = sc;
  __syncthreads();
  int prefix = sc - cnt;                 // exclusive within wave
  for (int w = 0; w < wv; ++w) prefix += wsum[w];

  float o[8];
#pragma unroll
  for (int k = 0; k < 8; ++k) {
    int   v = acc[k];
    int   a = v < 0 ? -v : v;
    float sg = v > 0 ? 1.0f : (v < 0 ? -1.0f : 0.0f);
    float r = 0.0f;
    if (a > T) {
      r = sg;
    } else if (a == T) {
      if (prefix < Q) r = sg;            // stable ties: lower index first
      prefix++;
    }
    o[k] = r;
  }
  float4* op = (float4*)(out + (size_t)b * DIM + t * 8);
  op[0] = make_float4(o[0], o[1], o[2], o[3]);
  op[1] = make_float4(o[4], o[5], o[6], o[7]);
}

extern "C" void kernel_launch(void* const* d_in, const int* in_sizes, int n_in,
                              void* d_out, int out_size, void* d_ws, size_t ws_size,
                              hipStream_t stream) {
  (void)in_sizes; (void)n_in; (void)out_size;
  const float* signal = (const float*)d_in[0];
  float* out = (float*)d_out;
  const size_t table_bytes = (size_t)NSEED * (DIM / 8);   // 512 KB bit-packed

  if (ws_size >= table_bytes) {
    uint16_t* tbl16 = (uint16_t*)d_ws;
    build_table_kernel<<<NSEED, 256, 0, stream>>>(tbl16);
    row_kernel<true><<<B_ROWS, 512, 0, stream>>>(signal, (const uint8_t*)d_ws, out);
  } else {
    row_kernel<false><<<B_ROWS, 512, 0, stream>>>(signal, nullptr, out);
  }
}

// Round 3
// 82.191 us; speedup vs baseline: 1.2551x; 1.0212x over previous
//
#include <hip/hip_runtime.h>
#include <stdint.h>

// HypervectorEngine: signal (512,8192) f32 -> sparse (512,4096) f32 in {-1,0,+1}
// Bit-exact replica of JAX reference (threefry partitionable path; absmax=0
// verified R1/R2). seed = pos ^ rne(v*1000) < 1024 -> only 1024 distinct
// hypervectors: build a BIT-PACKED table (1024 x 512 B = 512 KB, L2-resident),
// then per-row gather-sum + exact stable top-k(2048) by |sum| with sign emit.
//
// R3: row kernel gathers DWORDS (32 dims/load) with samples split 4-way across
// thread groups + byte-packed LDS reduce -> 4x fewer VMEM instructions.

#define B_ROWS 512
#define SIG_L  8192
#define DIM    4096
#define NS     100
#define NKEY   2048
#define NSEED  1024

__device__ __forceinline__ void tf2x32(uint32_t k0, uint32_t k1,
                                       uint32_t& x0, uint32_t& x1) {
  const uint32_t k2 = k0 ^ k1 ^ 0x1BD11BDAu;
  x0 += k0; x1 += k1;
#define TF_RND(r) { x0 += x1; x1 = (x1 << (r)) | (x1 >> (32 - (r))); x1 ^= x0; }
  TF_RND(13) TF_RND(15) TF_RND(26) TF_RND(6)
  x0 += k1; x1 += k2 + 1u;
  TF_RND(17) TF_RND(29) TF_RND(16) TF_RND(24)
  x0 += k2; x1 += k0 + 2u;
  TF_RND(13) TF_RND(15) TF_RND(26) TF_RND(6)
  x0 += k0; x1 += k1 + 3u;
  TF_RND(17) TF_RND(29) TF_RND(16) TF_RND(24)
  x0 += k1; x1 += k2 + 4u;
  TF_RND(13) TF_RND(15) TF_RND(26) TF_RND(6)
  x0 += k2; x1 += k0 + 5u;
#undef TF_RND
}

// 32 random bits for element i under folded key (partitionable path).
__device__ __forceinline__ uint32_t rbits32(uint32_t k0, uint32_t k1, uint32_t i) {
  uint32_t x0 = 0u, x1 = i;
  tf2x32(k0, k1, x0, x1);
  return x0 ^ x1;
}

// ---- Kernel A: bit-packed table. bit=1 <=> element is -1 (top bit of rbits).
// Layout: table[seed] is 512 B; little-endian, bit p of dword j = dim 32j+p.
__global__ __launch_bounds__(256) void build_table_kernel(uint16_t* __restrict__ tbl16) {
  const int seed = blockIdx.x;
  __shared__ uint32_t kk[2];
  if (threadIdx.x == 0) {
    uint32_t x0 = 0u, x1 = (uint32_t)seed;   // fold_in: cipher((0,42),(0,seed))
    tf2x32(0u, 42u, x0, x1);
    kk[0] = x0; kk[1] = x1;
  }
  __syncthreads();
  const uint32_t k0 = kk[0], k1 = kk[1];
  const int base = threadIdx.x * 16;         // 16 consecutive dims per thread
  uint32_t bits16 = 0;
#pragma unroll
  for (int k = 0; k < 16; ++k) {
    uint32_t b = rbits32(k0, k1, (uint32_t)(base + k)) >> 31;
    bits16 |= b << k;
  }
  tbl16[seed * 256 + threadIdx.x] = (uint16_t)bits16;   // 128 B/wave coalesced
}

// ---- Kernel B (table path): one block (512 thr) per row.
// Thread t: dim-group j=t&127 (dims 32j..32j+31), sample-residue g=t>>7
// (samples s = g, g+4, ..., 25 each). Byte-packed minus-counts, LDS-reduced.
__global__ __launch_bounds__(512) void row_kernel_t(const float* __restrict__ signal,
                                                    const uint32_t* __restrict__ tbl32,
                                                    float* __restrict__ out) {
  const int b = blockIdx.x;
  const int t = threadIdx.x;
  const int j = t & 127;
  const int g = t >> 7;
  __shared__ int      sseed[NS];
  __shared__ int      hist[101];     // |combined| in [0,100]
  __shared__ int      wsum[8];
  __shared__ int      TQ[2];
  __shared__ uint32_t red[512 * 9];  // stride 9 -> conflict-free

  if (t < 101) hist[t] = 0;
  if (t < NS) {
    const float step = 8191.0f / 99.0f;            // linspace(0, L-1, 100) step
    float idxf = (float)t * step;
    int   idx  = (int)idxf;                         // astype(int32): trunc
    float v    = signal[b * SIG_L + idx];
    int   val  = __float2int_rn(v * 1000.0f);       // jnp.round: half-to-even
    sseed[t] = t ^ val;                             // pos ^ val_seed (< 1024)
  }
  __syncthreads();

  // 25 dword gathers; c[q] = byte-packed minus-counts for dims 32j+4q..+3.
  uint32_t c[8];
#pragma unroll
  for (int q = 0; q < 8; ++q) c[q] = 0;
#pragma unroll 5
  for (int s = g; s < NS; s += 4) {
    const uint32_t m = tbl32[(sseed[s] << 7) + j];
#pragma unroll
    for (int q = 0; q < 8; ++q)
      c[q] += (((m >> (4 * q)) & 0xFu) * 0x00204081u) & 0x01010101u;
  }
#pragma unroll
  for (int q = 0; q < 8; ++q) red[t * 9 + q] = c[q];
  __syncthreads();

  // Reduce the 4 sample-groups (bytes <=25 each, sum <=100: no carry).
  if (t < 128) {
#pragma unroll
    for (int q = 0; q < 8; ++q) {
      uint32_t s0 = red[(j       ) * 9 + q] + red[(j + 128) * 9 + q];
      uint32_t s1 = red[(j + 256) * 9 + q] + red[(j + 384) * 9 + q];
      red[j * 9 + q] = s0 + s1;
    }
  }
  __syncthreads();

  // Back to 8 dims/thread: dims 8t..8t+7 = global words 2t, 2t+1.
  const uint32_t cw0 = red[(t >> 2) * 9 + 2 * (t & 3)];
  const uint32_t cw1 = red[(t >> 2) * 9 + 2 * (t & 3) + 1];
  int acc[8];
#pragma unroll
  for (int k = 0; k < 4; ++k) {
    acc[k]     = NS - 2 * (int)((cw0 >> (8 * k)) & 0xFFu);
    acc[k + 4] = NS - 2 * (int)((cw1 >> (8 * k)) & 0xFFu);
  }

  // Histogram of |combined| (values even, in [0,100]).
#pragma unroll
  for (int k = 0; k < 8; ++k) {
    int a = acc[k] < 0 ? -acc[k] : acc[k];
    atomicAdd(&hist[a], 1);
  }
  __syncthreads();

  // Threshold T + tie quota Q: parallel per-bin suffix sums (101 threads).
  if (t < 101) {
    int cum = 0;
    for (int x = t + 1; x <= 100; ++x) cum += hist[x];
    if (cum < NKEY && cum + hist[t] >= NKEY) { TQ[0] = t; TQ[1] = NKEY - cum; }
  }
  __syncthreads();
  const int T = TQ[0];
  const int Q = TQ[1];

  // Exclusive prefix of tie counts in dim order: wave shfl-scan + wave offsets.
  int cnt = 0;
#pragma unroll
  for (int k = 0; k < 8; ++k) {
    int a = acc[k] < 0 ? -acc[k] : acc[k];
    cnt += (a == T);
  }
  const int lane = t & 63, wv = t >> 6;
  int sc = cnt;
#pragma unroll
  for (int off = 1; off < 64; off <<= 1) {
    int n = __shfl_up(sc, off, 64);
    if (lane >= off) sc += n;
  }
  if (lane == 63) wsum[wv] = sc;
  __syncthreads();
  int prefix = sc - cnt;                 // exclusive within wave
  for (int w = 0; w < wv; ++w) prefix += wsum[w];

  float o[8];
#pragma unroll
  for (int k = 0; k < 8; ++k) {
    int   v = acc[k];
    int   a = v < 0 ? -v : v;
    float sg = v > 0 ? 1.0f : (v < 0 ? -1.0f : 0.0f);
    float r = 0.0f;
    if (a > T) {
      r = sg;
    } else if (a == T) {
      if (prefix < Q) r = sg;            // stable ties: lower index first
      prefix++;
    }
    o[k] = r;
  }
  float4* op = (float4*)(out + (size_t)b * DIM + t * 8);
  op[0] = make_float4(o[0], o[1], o[2], o[3]);
  op[1] = make_float4(o[4], o[5], o[6], o[7]);
}

// ---- Fallback (ws too small): on-the-fly ciphers, 8 dims/thread ----
__global__ __launch_bounds__(512) void row_kernel_f(const float* __restrict__ signal,
                                                    float* __restrict__ out) {
  const int b = blockIdx.x;
  const int t = threadIdx.x;
  __shared__ uint32_t sk0[NS], sk1[NS];
  __shared__ int      hist[101];
  __shared__ int      wsum[8];
  __shared__ int      TQ[2];

  if (t < 101) hist[t] = 0;
  if (t < NS) {
    const float step = 8191.0f / 99.0f;
    int   idx  = (int)((float)t * step);
    float v    = signal[b * SIG_L + idx];
    int   val  = __float2int_rn(v * 1000.0f);
    int   sd   = t ^ val;
    uint32_t x0 = 0u, x1 = (uint32_t)sd;
    tf2x32(0u, 42u, x0, x1);
    sk0[t] = x0; sk1[t] = x1;
  }
  __syncthreads();

  uint32_t c_lo = 0, c_hi = 0;
  for (int s = 0; s < NS; ++s) {
    uint32_t m = 0;
    const uint32_t k0 = sk0[s], k1 = sk1[s];
    for (int jj = 0; jj < 8; ++jj)
      m |= (rbits32(k0, k1, (uint32_t)(8 * t + jj)) >> 31) << jj;
    c_lo += ((m & 0xFu) * 0x00204081u) & 0x01010101u;
    c_hi += ((m >> 4)   * 0x00204081u) & 0x01010101u;
  }
  int acc[8];
#pragma unroll
  for (int k = 0; k < 4; ++k) {
    acc[k]     = NS - 2 * (int)((c_lo >> (8 * k)) & 0xFFu);
    acc[k + 4] = NS - 2 * (int)((c_hi >> (8 * k)) & 0xFFu);
  }
#pragma unroll
  for (int k = 0; k < 8; ++k) {
    int a = acc[k] < 0 ? -acc[k] : acc[k];
    atomicAdd(&hist[a], 1);
  }
  __syncthreads();
  if (t < 101) {
    int cum = 0;
    for (int x = t + 1; x <= 100; ++x) cum += hist[x];
    if (cum < NKEY && cum + hist[t] >= NKEY) { TQ[0] = t; TQ[1] = NKEY - cum; }
  }
  __syncthreads();
  const int T = TQ[0];
  const int Q = TQ[1];
  int cnt = 0;
#pragma unroll
  for (int k = 0; k < 8; ++k) {
    int a = acc[k] < 0 ? -acc[k] : acc[k];
    cnt += (a == T);
  }
  const int lane = t & 63, wv = t >> 6;
  int sc = cnt;
#pragma unroll
  for (int off = 1; off < 64; off <<= 1) {
    int n = __shfl_up(sc, off, 64);
    if (lane >= off) sc += n;
  }
  if (lane == 63) wsum[wv] = sc;
  __syncthreads();
  int prefix = sc - cnt;
  for (int w = 0; w < wv; ++w) prefix += wsum[w];
  float o[8];
#pragma unroll
  for (int k = 0; k < 8; ++k) {
    int   v = acc[k];
    int   a = v < 0 ? -v : v;
    float sg = v > 0 ? 1.0f : (v < 0 ? -1.0f : 0.0f);
    float r = 0.0f;
    if (a > T) r = sg;
    else if (a == T) { if (prefix < Q) r = sg; prefix++; }
    o[k] = r;
  }
  float4* op = (float4*)(out + (size_t)b * DIM + t * 8);
  op[0] = make_float4(o[0], o[1], o[2], o[3]);
  op[1] = make_float4(o[4], o[5], o[6], o[7]);
}

extern "C" void kernel_launch(void* const* d_in, const int* in_sizes, int n_in,
                              void* d_out, int out_size, void* d_ws, size_t ws_size,
                              hipStream_t stream) {
  (void)in_sizes; (void)n_in; (void)out_size;
  const float* signal = (const float*)d_in[0];
  float* out = (float*)d_out;
  const size_t table_bytes = (size_t)NSEED * (DIM / 8);   // 512 KB bit-packed

  if (ws_size >= table_bytes) {
    build_table_kernel<<<NSEED, 256, 0, stream>>>((uint16_t*)d_ws);
    row_kernel_t<<<B_ROWS, 512, 0, stream>>>(signal, (const uint32_t*)d_ws, out);
  } else {
    row_kernel_f<<<B_ROWS, 512, 0, stream>>>(signal, out);
  }
}